// Round 14
// baseline (1436.760 us; speedup 1.0000x reference)
//
#include <hip/hip_runtime.h>
#include <math.h>
#include <stddef.h>
#include <stdint.h>

// ---------------------------------------------------------------------------
// ReNet: patches -> vert bidir LSTM -> horiz bidir LSTM -> dense+relu
// B=64, I=J=32, C=3 -> D=12, HID=256, FC=1024.
// Round 14: r11 sweep shape (112 VGPR, spill-free) + register-neutral issue
// reorder: persistent cross-step bfr ring (R addrs are t-invariant), all zx
// loads batched after MFMA, out-copy stores after all loads, t-branch
// removed via zeroed hprev. r13's dual-q (spilled) reverted.
// ---------------------------------------------------------------------------

namespace {

typedef __bf16 bf16x8 __attribute__((ext_vector_type(8)));
typedef float f32x4 __attribute__((ext_vector_type(4)));
typedef __attribute__((address_space(1))) unsigned int as1_uint;
typedef __attribute__((address_space(3))) unsigned int as3_uint;

__device__ __forceinline__ float bf2f(ushort u) {
  return __builtin_bit_cast(float, (unsigned int)u << 16);
}
__device__ __forceinline__ ushort f2bf(float f) {
  unsigned int u = __builtin_bit_cast(unsigned int, f);
  u += 0x7fffu + ((u >> 16) & 1u);
  return (ushort)(u >> 16);
}
__device__ __forceinline__ unsigned int packbf(float a, float b) {
  return (unsigned int)f2bf(a) | ((unsigned int)f2bf(b) << 16);
}
__device__ __forceinline__ float sigm(float x) {
  return __fdividef(1.f, 1.f + __expf(-x));
}
__device__ __forceinline__ float tanh_(float x) {
  return 2.f * sigm(2.f * x) - 1.f;
}
__device__ __forceinline__ f32x4 mfma16(bf16x8 a, bf16x8 b, f32x4 c) {
  return __builtin_amdgcn_mfma_f32_16x16x32_bf16(a, b, c, 0, 0, 0);
}
__device__ __forceinline__ void load_lds16(const void* g, void* l) {
  __builtin_amdgcn_global_load_lds((const as1_uint*)g, (as3_uint*)l, 16, 0, 0);
}

// Zf fragment-major layout, per (dir, rb16) [rb16 = 16-row group, 0..127]:
// 65536 uint4. index = ((seq*2 + q)*2 + p)*512 + tidz ; components = gates.
// uint packs bf16 local rows (2*n2l, 2*n2l+1), n2l = kg*2+p (0..7),
// tidz = w*64 + kg*16 + l16 (== tid for 512 thr), hcol = w*32 + q*16 + l16.
// dir stride = 128*65536 uint4.

// --------------------------------------------------------------------------
__global__ __launch_bounds__(256) void transpose_bf16(
    const float* __restrict__ in, ushort* __restrict__ out, int K) {
  const int idx = blockIdx.x * 256 + threadIdx.x;
  if (idx >= (K << 10)) return;
  const int n = idx / K, k = idx - n * K;
  out[idx] = f2bf(in[k * 1024 + n]);
}

// --------------------------------------------------------------------------
// Repack recurrent weights r [256][1024] f32 into MFMA B-fragment-major bf16
__global__ __launch_bounds__(256) void rfrag_kernel(
    const float* __restrict__ r, ushort* __restrict__ out) {
  const int id = blockIdx.x * 256 + threadIdx.x;  // 32768 ids
  const int lane = id & 63, kc = (id >> 6) & 7, tile = id >> 9;
  const int kbase = (kc << 5) + ((lane >> 4) << 3);
  const int col = (tile << 4) + (lane & 15);
  ushort tmp[8];
#pragma unroll
  for (int j = 0; j < 8; ++j) tmp[j] = f2bf(r[(size_t)(kbase + j) * 1024 + col]);
  *(uint4*)&out[(size_t)id << 3] = *(const uint4*)tmp;
}

// --------------------------------------------------------------------------
// Vertical input projection -> fragment-major Zf. Block (jp, b, dir), 256 thr.
__global__ __launch_bounds__(256) void zxv3_kernel(
    const float* __restrict__ x, const float* __restrict__ k0_,
    const float* __restrict__ b0_, const float* __restrict__ k1_,
    const float* __restrict__ b1_, uint4* __restrict__ Zf) {
  const int tid = threadIdx.x;
  const int jp = blockIdx.x, b = blockIdx.y, dir = blockIdx.z;
  const int j0 = jp << 1;
  const float* kw_ = dir ? k1_ : k0_;
  const float* bw_ = dir ? b1_ : b0_;
  __shared__ float ps[2][32][12];
  for (int e = tid; e < 2 * 32 * 12; e += 256) {
    const int jj = e / 384, rest = e - jj * 384;
    const int i = rest / 12, qq = rest - i * 12;
    const int pr = qq / 6, rem = qq - pr * 6;
    ps[jj][i][qq] =
        x[((size_t)((b * 64 + i * 2 + pr) * 64) + (j0 + jj) * 2 + rem / 3) * 3 + rem % 3];
  }
  __syncthreads();
  float kr[12][4], br[4];
#pragma unroll
  for (int qq = 0; qq < 12; ++qq)
#pragma unroll
    for (int g = 0; g < 4; ++g) kr[qq][g] = kw_[qq * 1024 + (g << 8) + tid];
#pragma unroll
  for (int g = 0; g < 4; ++g) br[g] = bw_[(g << 8) + tid];

  const int wv = tid >> 5, qv = (tid >> 4) & 1, l16v = tid & 15;
  const int rb16 = (b << 1) + (jp >> 3);
  const int n2l = jp & 7;
  const int kgz = n2l >> 1, pz = n2l & 1;
  const int tidz = (wv << 6) + (kgz << 4) + l16v;
  uint4* base = Zf + ((size_t)dir * 128 + rb16) * 65536;

  for (int i = 0; i < 32; ++i) {
    float z0[4], z1[4];
#pragma unroll
    for (int g = 0; g < 4; ++g) { z0[g] = br[g]; z1[g] = br[g]; }
#pragma unroll
    for (int qq = 0; qq < 12; ++qq) {
      const float p0 = ps[0][i][qq], p1 = ps[1][i][qq];
#pragma unroll
      for (int g = 0; g < 4; ++g) {
        z0[g] += p0 * kr[qq][g];
        z1[g] += p1 * kr[qq][g];
      }
    }
    uint4 o;
    o.x = packbf(z0[0], z1[0]);
    o.y = packbf(z0[1], z1[1]);
    o.z = packbf(z0[2], z1[2]);
    o.w = packbf(z0[3], z1[3]);
    base[(size_t)((((i << 1) + qv) << 1) + pz) * 512 + tidz] = o;
  }
}

// --------------------------------------------------------------------------
// Self-contained bidirectional LSTM sweep, round 14 (persistent ring).
// Grid (128 rowblk, 2 dir) = 256 blocks (1/CU), 512 threads (8 waves).
// Block owns rows [rb*16,+16) x all 256 h; wave w owns h-cols [w*32,+32),
// passes q=0,1 sequential (acc/epilogue per q -> live set == r11's 112).
// Key reorder vs r11 (register-neutral):
//  - bfr ring PERSISTENT across q and t (R addrs t-invariant): q0-kc7 issues
//    q1-kc0 (covered by epilogue q0); q1-kc7 issues next-step q0-kc0
//    (covered by epilogue q1 + zx + out-copy + barrier).
//  - all 4 zx loads batched AFTER both kc-loops (reuse dead regs).
//  - out-copy stores AFTER all loads (stores no longer poison bfr waits).
//  - t-branch removed: hbuf[1] zeroed, t=0 MFMA on zeros (exact).
__global__ __launch_bounds__(512) void lstm_sweep10(
    const uint4* __restrict__ Zf, const uint4* __restrict__ rF,
    ushort* __restrict__ outbuf, int vert) {
  const int tid = threadIdx.x;
  const int lane = tid & 63, w = tid >> 6;
  const int l16 = lane & 15, kg = lane >> 4;
  const int rb = blockIdx.x, dir = (int)blockIdx.y;
  const int rowbase = rb << 4;

  __shared__ ushort hbuf[2][16 * 256];  // 2 x 8 KB, 16B-chunk XOR swizzle

  const uint4* rFd = rF + (size_t)dir * 32768;  // [64 tiles][8 kc][64 lanes]
  const uint4* zb = Zf + ((size_t)dir * 128 + rb) * 65536;

  // zero h(t=-1) buffer (hbuf[1]); 512 thr x 16B = 8 KB
  *(uint4*)((char*)hbuf[1] + tid * 16) = (uint4){0u, 0u, 0u, 0u};
  __syncthreads();

  float cst[2][4];  // [q][r]
#pragma unroll
  for (int q = 0; q < 2; ++q)
#pragma unroll
    for (int r = 0; r < 4; ++r) cst[q][r] = 0.f;

  // persistent zx regs (consumed at acc-init, reloaded end-of-step)
  uint4 zx[2][2];  // [q][p], components = gates
  {
    const int seq0 = dir ? 31 : 0;
#pragma unroll
    for (int q = 0; q < 2; ++q) {
      zx[q][0] = zb[(size_t)(((seq0 << 1) + q) << 1) * 512 + tid];
      zx[q][1] = zb[(size_t)((((seq0 << 1) + q) << 1) + 1) * 512 + tid];
    }
  }
  // persistent bfr ring; prologue: q0-kc0 -> slot 0
  uint4 bfr[2][4];
#pragma unroll
  for (int g = 0; g < 4; ++g)
    bfr[0][g] = rFd[(size_t)(((g << 4) + (w << 1)) << 3) * 64 + lane];

  for (int t = 0; t < 32; ++t) {
    const ushort* hprev = hbuf[(t + 1) & 1];
    ushort* hnext = hbuf[t & 1];

#pragma unroll
    for (int q = 0; q < 2; ++q) {
      // ---- acc init = zx ----
      f32x4 acc[4];
#pragma unroll
      for (int g = 0; g < 4; ++g) {
        const unsigned int u0 = (g == 0) ? zx[q][0].x : (g == 1) ? zx[q][0].y
                                : (g == 2) ? zx[q][0].z : zx[q][0].w;
        const unsigned int u1 = (g == 0) ? zx[q][1].x : (g == 1) ? zx[q][1].y
                                : (g == 2) ? zx[q][1].z : zx[q][1].w;
        acc[g][0] = bf2f((ushort)(u0 & 0xffffu));
        acc[g][1] = bf2f((ushort)(u0 >> 16));
        acc[g][2] = bf2f((ushort)(u1 & 0xffffu));
        acc[g][3] = bf2f((ushort)(u1 >> 16));
      }

      // ---- kc-ring MFMA; ring slot parity: kc0 of each q is in slot 0 ----
#pragma unroll
      for (int kc = 0; kc < 8; ++kc) {
        const int cur = kc & 1;
        if (kc < 7) {
          // next kc of this q
#pragma unroll
          for (int g = 0; g < 4; ++g)
            bfr[cur ^ 1][g] =
                rFd[((size_t)(((g << 4) + (w << 1) + q) << 3) + kc + 1) * 64 +
                    lane];
        } else {
          // q0: issue q1-kc0 (covered by epilogue q0).
          // q1: issue next-step q0-kc0 (same addr every step; covered by
          //     zx + out-copy + epilogue q1 + barrier).
#pragma unroll
          for (int g = 0; g < 4; ++g)
            bfr[cur ^ 1][g] =
                rFd[(size_t)(((g << 4) + (w << 1) + (q ^ 1)) << 3) * 64 + lane];
        }
        const int c4 = (kc << 2) + kg;
        const uint4 a = *(const uint4*)((const char*)hprev + l16 * 512 +
                                        ((c4 ^ (l16 & 7)) << 4));
        const bf16x8 ab = __builtin_bit_cast(bf16x8, a);
#pragma unroll
        for (int g = 0; g < 4; ++g)
          acc[g] = mfma16(ab, __builtin_bit_cast(bf16x8, bfr[cur][g]), acc[g]);
      }

      if (q == 1) {
        // ---- next-step zx loads (after ALL bfr issues; regs dead) ----
        if (t < 31) {
          const int seqn = dir ? (30 - t) : (t + 1);
#pragma unroll
          for (int qq = 0; qq < 2; ++qq) {
            zx[qq][0] = zb[(size_t)(((seqn << 1) + qq) << 1) * 512 + tid];
            zx[qq][1] = zb[(size_t)((((seqn << 1) + qq) << 1) + 1) * 512 + tid];
          }
        }
        // ---- out-copy of h(t-1) (stores after all loads) ----
        if (t) {
          const int seqP = dir ? (32 - t) : (t - 1);
          const int row = tid >> 5, c4o = tid & 31;
          const uint4 v = *(const uint4*)((const char*)hprev + row * 512 +
                                          ((c4o ^ (row & 7)) << 4));
          const int n = rowbase + row, b = n >> 5, sp = n & 31;
          const int X = vert ? seqP : sp, Y = vert ? sp : seqP;
          *(uint4*)&outbuf[(((size_t)(b * 32 + X) * 32 + Y) << 9) + (dir << 8) +
                           (c4o << 3)] = v;
        }
      }

      // ---- gate epilogue -> h(t) into LDS only ----
      const int col = (w << 5) + (q << 4) + l16;
#pragma unroll
      for (int r = 0; r < 4; ++r) {
        const float zi = acc[0][r];
        const float zf = acc[1][r];
        const float zg = acc[2][r];
        const float zo = acc[3][r];
        const float cn = sigm(zf) * cst[q][r] + sigm(zi) * tanh_(zg);
        cst[q][r] = cn;
        const float hv = sigm(zo) * tanh_(cn);
        const int row = (kg << 2) + r;
        *(ushort*)((char*)hnext + row * 512 +
                   (((col >> 3) ^ (row & 7)) << 4) + ((col & 7) << 1)) =
            f2bf(hv);
      }
    }
    __syncthreads();  // h(t) complete; all h(t-1) reads done
  }

  // ---- final copy of h(31) ----
  {
    const int seqP = dir ? 0 : 31;
    const ushort* hl = hbuf[1];  // t=31 wrote hbuf[1]
    const int row = tid >> 5, c4o = tid & 31;
    const uint4 v = *(const uint4*)((const char*)hl + row * 512 +
                                    ((c4o ^ (row & 7)) << 4));
    const int n = rowbase + row, b = n >> 5, sp = n & 31;
    const int X = vert ? seqP : sp, Y = vert ? sp : seqP;
    *(uint4*)&outbuf[(((size_t)(b * 32 + X) * 32 + Y) << 9) + (dir << 8) +
                     (c4o << 3)] = v;
  }
}

// --------------------------------------------------------------------------
// C = A[M][512] @ BT[1024][512]^T + bias. 128x128 tile, BK=64,
// global_load_lds + XOR swizzle, XCD-aware remap, LDS-staged epilogue.
// EPI 0: N = 4 gates x 32 hcols (gate-split), writes fragment-major Zf.
// EPI 1: N contiguous, relu f32 store.
template <int EPI>
__global__ __launch_bounds__(256) void gemm_bt(
    const ushort* __restrict__ A, const ushort* __restrict__ BT,
    const float* __restrict__ bias, void* __restrict__ Cv) {
  const int tid = threadIdx.x;
  const int lane = tid & 63, wid = tid >> 6;
  const int l16 = lane & 15, kg = lane >> 4;
  const int wr = wid >> 1, wc = wid & 1;
  const int bid = blockIdx.x;
  const int xcd = bid & 7, lid = bid >> 3;
  const int m0 = ((xcd << 6) + (lid >> 3)) << 7;
  const int nblk = lid & 7;
  const int hc0 = nblk << 5;   // EPI0: 32 hcols x 4 gates
  const int n0 = nblk << 7;    // EPI1: 128 contiguous cols

  union SM {
    struct { uint4 A[128][8]; uint4 B[128][8]; } k;
    ushort eh[64][136];
    float ef[64][132];
  };
  __shared__ SM sm;

  f32x4 acc[4][4];
#pragma unroll
  for (int mt = 0; mt < 4; ++mt)
#pragma unroll
    for (int nt = 0; nt < 4; ++nt) acc[mt][nt] = (f32x4){0.f, 0.f, 0.f, 0.f};

  for (int k0 = 0; k0 < 512; k0 += 64) {
#pragma unroll
    for (int c = 0; c < 4; ++c) {
      const int cid = (wid << 8) + (c << 6) + lane;
      const int row = cid >> 3, ch = cid & 7;
      const int sch = ch ^ (row & 7);
      const int brow = (EPI == 0) ? (((row >> 5) << 8) + hc0 + (row & 31))
                                  : (n0 + row);
      load_lds16(A + (size_t)(m0 + row) * 512 + k0 + (sch << 3),
                 (uint4*)sm.k.A + (cid - lane));
      load_lds16(BT + (size_t)brow * 512 + k0 + (sch << 3),
                 (uint4*)sm.k.B + (cid - lane));
    }
    __syncthreads();
#pragma unroll
    for (int kk = 0; kk < 2; ++kk) {
      const int q = (kk << 2) + kg;
      bf16x8 a[4], b[4];
#pragma unroll
      for (int mt = 0; mt < 4; ++mt) {
        const int rr = (wr << 6) + (mt << 4) + l16;
        a[mt] = __builtin_bit_cast(bf16x8, sm.k.A[rr][q ^ (rr & 7)]);
      }
#pragma unroll
      for (int nt = 0; nt < 4; ++nt) {
        const int rr = (wc << 6) + (nt << 4) + l16;
        b[nt] = __builtin_bit_cast(bf16x8, sm.k.B[rr][q ^ (rr & 7)]);
      }
#pragma unroll
      for (int mt = 0; mt < 4; ++mt)
#pragma unroll
        for (int nt = 0; nt < 4; ++nt)
          acc[mt][nt] = mfma16(a[mt], b[nt], acc[mt][nt]);
    }
    __syncthreads();
  }

  float bn[4];
#pragma unroll
  for (int nt = 0; nt < 4; ++nt) {
    const int lcol = (wc << 6) + (nt << 4) + l16;
    const int gn = (EPI == 0) ? (((lcol >> 5) << 8) + hc0 + (lcol & 31))
                              : (n0 + lcol);
    bn[nt] = bias[gn];
  }

#pragma unroll
  for (int h = 0; h < 2; ++h) {
    __syncthreads();
    if (wr == h) {
#pragma unroll
      for (int nt = 0; nt < 4; ++nt) {
        const int col = (wc << 6) + (nt << 4) + l16;
#pragma unroll
        for (int mt = 0; mt < 4; ++mt) {
#pragma unroll
          for (int r = 0; r < 4; ++r) {
            const int rowl = (mt << 4) + (kg << 2) + r;
            const float v = acc[mt][nt][r] + bn[nt];
            if (EPI == 0)
              sm.eh[rowl][col] = f2bf(v);
            else
              sm.ef[rowl][col] = fmaxf(v, 0.f);
          }
        }
      }
    }
    __syncthreads();
    if (EPI == 0) {
      // half h covers rows n_a = 2*((m0>>6)+h), n_b = n_a+1, x 32 seq.
      uint4* Cz = (uint4*)Cv;
      const int n_a = ((m0 >> 6) + h) << 1;
      const int rbz = n_a >> 4;
      const int n2l = (n_a & 15) >> 1;
      const int kgz = n2l >> 1, pz = n2l & 1;
#pragma unroll
      for (int it = 0; it < 4; ++it) {
        const int e = tid + (it << 8);  // 0..1023
        const int seq = e >> 5, hl = e & 31;
        const int qv = hl >> 4, l16v = hl & 15;
        const int wz = (hc0 + hl) >> 5;
        const int tidz = (wz << 6) + (kgz << 4) + l16v;
        uint4 o;
        o.x = (unsigned int)sm.eh[seq][hl] |
              ((unsigned int)sm.eh[32 + seq][hl] << 16);
        o.y = (unsigned int)sm.eh[seq][32 + hl] |
              ((unsigned int)sm.eh[32 + seq][32 + hl] << 16);
        o.z = (unsigned int)sm.eh[seq][64 + hl] |
              ((unsigned int)sm.eh[32 + seq][64 + hl] << 16);
        o.w = (unsigned int)sm.eh[seq][96 + hl] |
              ((unsigned int)sm.eh[32 + seq][96 + hl] << 16);
        Cz[(size_t)rbz * 65536 + (size_t)((((seq << 1) + qv) << 1) + pz) * 512 +
           tidz] = o;
      }
    } else {
      float* out = (float*)Cv;
#pragma unroll
      for (int q = 0; q < 8; ++q) {
        const int c = tid + (q << 8);
        const int row = c >> 5, co = (c & 31) << 2;
        typedef float f4v __attribute__((ext_vector_type(4)));
        const f4v v = *(const f4v*)&sm.ef[row][co];
        __builtin_nontemporal_store(
            v, (f4v*)(out + (size_t)(m0 + (h << 6) + row) * 1024 + n0 + co));
      }
    }
  }
}

}  // namespace

extern "C" void kernel_launch(void* const* d_in, const int* in_sizes, int n_in,
                              void* d_out, int out_size, void* d_ws, size_t ws_size,
                              hipStream_t stream) {
  (void)in_sizes; (void)n_in; (void)out_size; (void)ws_size;
  const float* x    = (const float*)d_in[0];
  const float* k_ud = (const float*)d_in[1];
  const float* r_ud = (const float*)d_in[2];
  const float* b_ud = (const float*)d_in[3];
  const float* k_du = (const float*)d_in[4];
  const float* r_du = (const float*)d_in[5];
  const float* b_du = (const float*)d_in[6];
  const float* k_lr = (const float*)d_in[7];
  const float* r_lr = (const float*)d_in[8];
  const float* b_lr = (const float*)d_in[9];
  const float* k_rl = (const float*)d_in[10];
  const float* r_rl = (const float*)d_in[11];
  const float* b_rl = (const float*)d_in[12];
  const float* Wd   = (const float*)d_in[13];
  const float* bd   = (const float*)d_in[14];

  ushort* W    = (ushort*)d_ws;
  ushort* Z    = W;                      // Zf: 2*128*65536 uint4 = 268 MB
  ushort* vbuf = Z + 134217728;          // [64][32][32][512]    33554432
  ushort* rF   = vbuf + 33554432;        // [4][64][8][64][8]     1048576
  ushort* kTh  = rF + 1048576;           // [2][1024][512]        1048576
  ushort* WdT  = kTh + 1048576;          // [1024][512]            524288
  uint4* Zf = (uint4*)Z;

  // ---- weight prep ----
  rfrag_kernel<<<128, 256, 0, stream>>>(r_ud, rF);
  rfrag_kernel<<<128, 256, 0, stream>>>(r_du, rF + 262144);
  rfrag_kernel<<<128, 256, 0, stream>>>(r_lr, rF + 524288);
  rfrag_kernel<<<128, 256, 0, stream>>>(r_rl, rF + 786432);
  transpose_bf16<<<2048, 256, 0, stream>>>(k_lr, kTh, 512);
  transpose_bf16<<<2048, 256, 0, stream>>>(k_rl, kTh + 524288, 512);
  transpose_bf16<<<2048, 256, 0, stream>>>(Wd, WdT, 512);

  // ---- vertical input projection (K=12) -> fragment-major Zf ----
  zxv3_kernel<<<dim3(16, 64, 2), 256, 0, stream>>>(x, k_ud, b_ud, k_du, b_du,
                                                   Zf);

  // ---- vertical sweep ----
  lstm_sweep10<<<dim3(128, 2), 512, 0, stream>>>(Zf, (const uint4*)rF, vbuf, 1);

  // ---- horizontal input projection: Zf = v @ k + b (per dir) ----
  gemm_bt<0><<<4096, 256, 0, stream>>>(vbuf, kTh, b_lr, (void*)Zf);
  gemm_bt<0><<<4096, 256, 0, stream>>>(vbuf, kTh + 524288, b_rl,
                                       (void*)(Zf + (size_t)128 * 65536));

  // ---- horizontal sweep (writes hfin over vbuf; reads only Zf) ----
  lstm_sweep10<<<dim3(128, 2), 512, 0, stream>>>(
      Zf, (const uint4*)(rF + 524288), vbuf, 0);

  // ---- dense + relu ----
  gemm_bt<1><<<4096, 256, 0, stream>>>(vbuf, WdT, bd, d_out);
}

// Round 15
// 1296.575 us; speedup vs baseline: 1.1081x; 1.1081x over previous
//
#include <hip/hip_runtime.h>
#include <math.h>
#include <stddef.h>
#include <stdint.h>

// ---------------------------------------------------------------------------
// ReNet: patches -> vert bidir LSTM -> horiz bidir LSTM -> dense+relu
// B=64, I=J=32, D=12, HID=256, FC=1024.
// Round 15: TLP sweep designed for the 64-reg budget: 1024 thr (16 waves,
// 4/SIMD), NO bfr ring, NO zx ping (live set ~59 regs). launch_bounds(1024)
// without a min-waves arg (r12's ",4" forced a 64-reg cap onto a ~110-reg
// body -> spill). All other kernels exactly r11.
// ---------------------------------------------------------------------------

namespace {

typedef __bf16 bf16x8 __attribute__((ext_vector_type(8)));
typedef float f32x4 __attribute__((ext_vector_type(4)));
typedef __attribute__((address_space(1))) unsigned int as1_uint;
typedef __attribute__((address_space(3))) unsigned int as3_uint;

__device__ __forceinline__ float bf2f(ushort u) {
  return __builtin_bit_cast(float, (unsigned int)u << 16);
}
__device__ __forceinline__ ushort f2bf(float f) {
  unsigned int u = __builtin_bit_cast(unsigned int, f);
  u += 0x7fffu + ((u >> 16) & 1u);
  return (ushort)(u >> 16);
}
__device__ __forceinline__ unsigned int packbf(float a, float b) {
  return (unsigned int)f2bf(a) | ((unsigned int)f2bf(b) << 16);
}
__device__ __forceinline__ float sigm(float x) {
  return __fdividef(1.f, 1.f + __expf(-x));
}
__device__ __forceinline__ float tanh_(float x) {
  return 2.f * sigm(2.f * x) - 1.f;
}
__device__ __forceinline__ f32x4 mfma16(bf16x8 a, bf16x8 b, f32x4 c) {
  return __builtin_amdgcn_mfma_f32_16x16x32_bf16(a, b, c, 0, 0, 0);
}
__device__ __forceinline__ void load_lds16(const void* g, void* l) {
  __builtin_amdgcn_global_load_lds((const as1_uint*)g, (as3_uint*)l, 16, 0, 0);
}

// Zf fragment-major layout, per (dir, rb16) [rb16 = 16-row group, 0..127]:
// 65536 uint4. index = ((seq*2 + q)*2 + p)*512 + tidz ; components = gates.
// uint packs bf16 local rows (2*n2l, 2*n2l+1), n2l = kg*2+p (0..7),
// tidz = w8*64 + kg*16 + l16, hcol = w8*32 + q*16 + l16.
// dir stride = 128*65536 uint4.

// --------------------------------------------------------------------------
__global__ __launch_bounds__(256) void transpose_bf16(
    const float* __restrict__ in, ushort* __restrict__ out, int K) {
  const int idx = blockIdx.x * 256 + threadIdx.x;
  if (idx >= (K << 10)) return;
  const int n = idx / K, k = idx - n * K;
  out[idx] = f2bf(in[k * 1024 + n]);
}

// --------------------------------------------------------------------------
// Repack recurrent weights r [256][1024] f32 into MFMA B-fragment-major bf16
__global__ __launch_bounds__(256) void rfrag_kernel(
    const float* __restrict__ r, ushort* __restrict__ out) {
  const int id = blockIdx.x * 256 + threadIdx.x;  // 32768 ids
  const int lane = id & 63, kc = (id >> 6) & 7, tile = id >> 9;
  const int kbase = (kc << 5) + ((lane >> 4) << 3);
  const int col = (tile << 4) + (lane & 15);
  ushort tmp[8];
#pragma unroll
  for (int j = 0; j < 8; ++j) tmp[j] = f2bf(r[(size_t)(kbase + j) * 1024 + col]);
  *(uint4*)&out[(size_t)id << 3] = *(const uint4*)tmp;
}

// --------------------------------------------------------------------------
// Vertical input projection -> fragment-major Zf. Block (jp, b, dir), 256 thr.
__global__ __launch_bounds__(256) void zxv3_kernel(
    const float* __restrict__ x, const float* __restrict__ k0_,
    const float* __restrict__ b0_, const float* __restrict__ k1_,
    const float* __restrict__ b1_, uint4* __restrict__ Zf) {
  const int tid = threadIdx.x;
  const int jp = blockIdx.x, b = blockIdx.y, dir = blockIdx.z;
  const int j0 = jp << 1;
  const float* kw_ = dir ? k1_ : k0_;
  const float* bw_ = dir ? b1_ : b0_;
  __shared__ float ps[2][32][12];
  for (int e = tid; e < 2 * 32 * 12; e += 256) {
    const int jj = e / 384, rest = e - jj * 384;
    const int i = rest / 12, qq = rest - i * 12;
    const int pr = qq / 6, rem = qq - pr * 6;
    ps[jj][i][qq] =
        x[((size_t)((b * 64 + i * 2 + pr) * 64) + (j0 + jj) * 2 + rem / 3) * 3 + rem % 3];
  }
  __syncthreads();
  float kr[12][4], br[4];
#pragma unroll
  for (int qq = 0; qq < 12; ++qq)
#pragma unroll
    for (int g = 0; g < 4; ++g) kr[qq][g] = kw_[qq * 1024 + (g << 8) + tid];
#pragma unroll
  for (int g = 0; g < 4; ++g) br[g] = bw_[(g << 8) + tid];

  const int wv = tid >> 5, qv = (tid >> 4) & 1, l16v = tid & 15;
  const int rb16 = (b << 1) + (jp >> 3);
  const int n2l = jp & 7;
  const int kgz = n2l >> 1, pz = n2l & 1;
  const int tidz = (wv << 6) + (kgz << 4) + l16v;
  uint4* base = Zf + ((size_t)dir * 128 + rb16) * 65536;

  for (int i = 0; i < 32; ++i) {
    float z0[4], z1[4];
#pragma unroll
    for (int g = 0; g < 4; ++g) { z0[g] = br[g]; z1[g] = br[g]; }
#pragma unroll
    for (int qq = 0; qq < 12; ++qq) {
      const float p0 = ps[0][i][qq], p1 = ps[1][i][qq];
#pragma unroll
      for (int g = 0; g < 4; ++g) {
        z0[g] += p0 * kr[qq][g];
        z1[g] += p1 * kr[qq][g];
      }
    }
    uint4 o;
    o.x = packbf(z0[0], z1[0]);
    o.y = packbf(z0[1], z1[1]);
    o.z = packbf(z0[2], z1[2]);
    o.w = packbf(z0[3], z1[3]);
    base[(size_t)((((i << 1) + qv) << 1) + pz) * 512 + tidz] = o;
  }
}

// --------------------------------------------------------------------------
// Self-contained bidirectional LSTM sweep, round 15 (pure TLP).
// Grid (128 rowblk, 2 dir) = 256 blocks (1/CU), 1024 threads = 16 waves
// (4/SIMD). Block owns rows [rb*16,+16) x all 256 h; wave w16 owns h-cols
// [w16*16,+16). No prefetch machinery: zx loaded at step start, bfr loaded
// per-kc (dependent) -- stalls hidden by 4 co-resident waves/SIMD. Live set
// ~59 VGPR (fits even a 64-reg cap; no spill). One barrier/step; out-copy
// of h(t-1) at step start (uint2/thread).
__global__ __launch_bounds__(1024) void lstm_sweep11(
    const uint4* __restrict__ Zf, const uint4* __restrict__ rF,
    ushort* __restrict__ outbuf, int vert) {
  const int tid = threadIdx.x;
  const int lane = tid & 63, w16 = tid >> 6;  // 0..15
  const int l16 = lane & 15, kg = lane >> 4;
  const int w8 = w16 >> 1, q = w16 & 1;
  const int rb = blockIdx.x, dir = (int)blockIdx.y;
  const int rowbase = rb << 4;

  __shared__ ushort hbuf[2][16 * 256];  // 2 x 8 KB, 16B-chunk XOR swizzle

  const uint4* rFd = rF + (size_t)dir * 32768;  // [64 tiles][8 kc][64 lanes]
  const uint4* zb = Zf + ((size_t)dir * 128 + rb) * 65536;
  const int tidz = (w8 << 6) + (kg << 4) + l16;

  float cst[4];
#pragma unroll
  for (int r = 0; r < 4; ++r) cst[r] = 0.f;

  for (int t = 0; t < 32; ++t) {
    const ushort* hprev = hbuf[(t + 1) & 1];
    ushort* hnext = hbuf[t & 1];
    const int seq = dir ? (31 - t) : t;

    // ---- out-copy of h(t-1), uint2 per thread ----
    if (t) {
      const int seqP = dir ? (32 - t) : (t - 1);
      const int row = tid >> 6, e8 = tid & 63;
      const int c4 = e8 >> 1, half = e8 & 1;
      const uint2 v = *(const uint2*)((const char*)hprev + row * 512 +
                                      ((c4 ^ (row & 7)) << 4) + (half << 3));
      const int n = rowbase + row, b = n >> 5, sp = n & 31;
      const int X = vert ? seqP : sp, Y = vert ? sp : seqP;
      *(uint2*)&outbuf[(((size_t)(b * 32 + X) * 32 + Y) << 9) + (dir << 8) +
                       (e8 << 2)] = v;
    }

    // ---- zx loads (step start; latency hidden by other waves) ----
    const uint4 zx0 = zb[(size_t)(((seq << 1) + q) << 1) * 512 + tidz];
    const uint4 zx1 = zb[(size_t)((((seq << 1) + q) << 1) + 1) * 512 + tidz];

    // ---- acc init = zx ----
    f32x4 acc[4];
#pragma unroll
    for (int g = 0; g < 4; ++g) {
      const unsigned int u0 = (g == 0) ? zx0.x : (g == 1) ? zx0.y
                              : (g == 2) ? zx0.z : zx0.w;
      const unsigned int u1 = (g == 0) ? zx1.x : (g == 1) ? zx1.y
                              : (g == 2) ? zx1.z : zx1.w;
      acc[g][0] = bf2f((ushort)(u0 & 0xffffu));
      acc[g][1] = bf2f((ushort)(u0 >> 16));
      acc[g][2] = bf2f((ushort)(u1 & 0xffffu));
      acc[g][3] = bf2f((ushort)(u1 >> 16));
    }

    // ---- MFMA: acc += h(t-1) @ R ; direct per-kc loads (no ring) ----
    if (t) {
#pragma unroll
      for (int kc = 0; kc < 8; ++kc) {
        uint4 bfr[4];
#pragma unroll
        for (int g = 0; g < 4; ++g)
          bfr[g] = rFd[((size_t)(((g << 4) + w16) << 3) + kc) * 64 + lane];
        const int c4 = (kc << 2) + kg;
        const uint4 a = *(const uint4*)((const char*)hprev + l16 * 512 +
                                        ((c4 ^ (l16 & 7)) << 4));
        const bf16x8 ab = __builtin_bit_cast(bf16x8, a);
#pragma unroll
        for (int g = 0; g < 4; ++g)
          acc[g] = mfma16(ab, __builtin_bit_cast(bf16x8, bfr[g]), acc[g]);
      }
    }

    // ---- gate epilogue -> h(t) into LDS only ----
    const int col = (w16 << 4) + l16;
#pragma unroll
    for (int r = 0; r < 4; ++r) {
      const float zi = acc[0][r];
      const float zf = acc[1][r];
      const float zg = acc[2][r];
      const float zo = acc[3][r];
      const float cn = sigm(zf) * cst[r] + sigm(zi) * tanh_(zg);
      cst[r] = cn;
      const float hv = sigm(zo) * tanh_(cn);
      const int row = (kg << 2) + r;
      *(ushort*)((char*)hnext + row * 512 +
                 (((col >> 3) ^ (row & 7)) << 4) + ((col & 7) << 1)) = f2bf(hv);
    }
    __syncthreads();  // h(t) complete; all h(t-1) reads done
  }

  // ---- final copy of h(31) ----
  {
    const int seqP = dir ? 0 : 31;
    const ushort* hl = hbuf[1];  // t=31 wrote hbuf[1]
    const int row = tid >> 6, e8 = tid & 63;
    const int c4 = e8 >> 1, half = e8 & 1;
    const uint2 v = *(const uint2*)((const char*)hl + row * 512 +
                                    ((c4 ^ (row & 7)) << 4) + (half << 3));
    const int n = rowbase + row, b = n >> 5, sp = n & 31;
    const int X = vert ? seqP : sp, Y = vert ? sp : seqP;
    *(uint2*)&outbuf[(((size_t)(b * 32 + X) * 32 + Y) << 9) + (dir << 8) +
                     (e8 << 2)] = v;
  }
}

// --------------------------------------------------------------------------
// C = A[M][512] @ BT[1024][512]^T + bias. 128x128 tile, BK=64,
// global_load_lds + XOR swizzle, XCD-aware remap, LDS-staged epilogue.
// EPI 0: N = 4 gates x 32 hcols (gate-split), writes fragment-major Zf.
// EPI 1: N contiguous, relu f32 store.
template <int EPI>
__global__ __launch_bounds__(256) void gemm_bt(
    const ushort* __restrict__ A, const ushort* __restrict__ BT,
    const float* __restrict__ bias, void* __restrict__ Cv) {
  const int tid = threadIdx.x;
  const int lane = tid & 63, wid = tid >> 6;
  const int l16 = lane & 15, kg = lane >> 4;
  const int wr = wid >> 1, wc = wid & 1;
  const int bid = blockIdx.x;
  const int xcd = bid & 7, lid = bid >> 3;
  const int m0 = ((xcd << 6) + (lid >> 3)) << 7;
  const int nblk = lid & 7;
  const int hc0 = nblk << 5;   // EPI0: 32 hcols x 4 gates
  const int n0 = nblk << 7;    // EPI1: 128 contiguous cols

  union SM {
    struct { uint4 A[128][8]; uint4 B[128][8]; } k;
    ushort eh[64][136];
    float ef[64][132];
  };
  __shared__ SM sm;

  f32x4 acc[4][4];
#pragma unroll
  for (int mt = 0; mt < 4; ++mt)
#pragma unroll
    for (int nt = 0; nt < 4; ++nt) acc[mt][nt] = (f32x4){0.f, 0.f, 0.f, 0.f};

  for (int k0 = 0; k0 < 512; k0 += 64) {
#pragma unroll
    for (int c = 0; c < 4; ++c) {
      const int cid = (wid << 8) + (c << 6) + lane;
      const int row = cid >> 3, ch = cid & 7;
      const int sch = ch ^ (row & 7);
      const int brow = (EPI == 0) ? (((row >> 5) << 8) + hc0 + (row & 31))
                                  : (n0 + row);
      load_lds16(A + (size_t)(m0 + row) * 512 + k0 + (sch << 3),
                 (uint4*)sm.k.A + (cid - lane));
      load_lds16(BT + (size_t)brow * 512 + k0 + (sch << 3),
                 (uint4*)sm.k.B + (cid - lane));
    }
    __syncthreads();
#pragma unroll
    for (int kk = 0; kk < 2; ++kk) {
      const int q = (kk << 2) + kg;
      bf16x8 a[4], b[4];
#pragma unroll
      for (int mt = 0; mt < 4; ++mt) {
        const int rr = (wr << 6) + (mt << 4) + l16;
        a[mt] = __builtin_bit_cast(bf16x8, sm.k.A[rr][q ^ (rr & 7)]);
      }
#pragma unroll
      for (int nt = 0; nt < 4; ++nt) {
        const int rr = (wc << 6) + (nt << 4) + l16;
        b[nt] = __builtin_bit_cast(bf16x8, sm.k.B[rr][q ^ (rr & 7)]);
      }
#pragma unroll
      for (int mt = 0; mt < 4; ++mt)
#pragma unroll
        for (int nt = 0; nt < 4; ++nt)
          acc[mt][nt] = mfma16(a[mt], b[nt], acc[mt][nt]);
    }
    __syncthreads();
  }

  float bn[4];
#pragma unroll
  for (int nt = 0; nt < 4; ++nt) {
    const int lcol = (wc << 6) + (nt << 4) + l16;
    const int gn = (EPI == 0) ? (((lcol >> 5) << 8) + hc0 + (lcol & 31))
                              : (n0 + lcol);
    bn[nt] = bias[gn];
  }

#pragma unroll
  for (int h = 0; h < 2; ++h) {
    __syncthreads();
    if (wr == h) {
#pragma unroll
      for (int nt = 0; nt < 4; ++nt) {
        const int col = (wc << 6) + (nt << 4) + l16;
#pragma unroll
        for (int mt = 0; mt < 4; ++mt) {
#pragma unroll
          for (int r = 0; r < 4; ++r) {
            const int rowl = (mt << 4) + (kg << 2) + r;
            const float v = acc[mt][nt][r] + bn[nt];
            if (EPI == 0)
              sm.eh[rowl][col] = f2bf(v);
            else
              sm.ef[rowl][col] = fmaxf(v, 0.f);
          }
        }
      }
    }
    __syncthreads();
    if (EPI == 0) {
      // half h covers rows n_a = 2*((m0>>6)+h), n_b = n_a+1, x 32 seq.
      uint4* Cz = (uint4*)Cv;
      const int n_a = ((m0 >> 6) + h) << 1;
      const int rbz = n_a >> 4;
      const int n2l = (n_a & 15) >> 1;
      const int kgz = n2l >> 1, pz = n2l & 1;
#pragma unroll
      for (int it = 0; it < 4; ++it) {
        const int e = tid + (it << 8);  // 0..1023
        const int seq = e >> 5, hl = e & 31;
        const int qv = hl >> 4, l16v = hl & 15;
        const int wz = (hc0 + hl) >> 5;
        const int tidz = (wz << 6) + (kgz << 4) + l16v;
        uint4 o;
        o.x = (unsigned int)sm.eh[seq][hl] |
              ((unsigned int)sm.eh[32 + seq][hl] << 16);
        o.y = (unsigned int)sm.eh[seq][32 + hl] |
              ((unsigned int)sm.eh[32 + seq][32 + hl] << 16);
        o.z = (unsigned int)sm.eh[seq][64 + hl] |
              ((unsigned int)sm.eh[32 + seq][64 + hl] << 16);
        o.w = (unsigned int)sm.eh[seq][96 + hl] |
              ((unsigned int)sm.eh[32 + seq][96 + hl] << 16);
        Cz[(size_t)rbz * 65536 + (size_t)((((seq << 1) + qv) << 1) + pz) * 512 +
           tidz] = o;
      }
    } else {
      float* out = (float*)Cv;
#pragma unroll
      for (int q = 0; q < 8; ++q) {
        const int c = tid + (q << 8);
        const int row = c >> 5, co = (c & 31) << 2;
        typedef float f4v __attribute__((ext_vector_type(4)));
        const f4v v = *(const f4v*)&sm.ef[row][co];
        __builtin_nontemporal_store(
            v, (f4v*)(out + (size_t)(m0 + (h << 6) + row) * 1024 + n0 + co));
      }
    }
  }
}

}  // namespace

extern "C" void kernel_launch(void* const* d_in, const int* in_sizes, int n_in,
                              void* d_out, int out_size, void* d_ws, size_t ws_size,
                              hipStream_t stream) {
  (void)in_sizes; (void)n_in; (void)out_size; (void)ws_size;
  const float* x    = (const float*)d_in[0];
  const float* k_ud = (const float*)d_in[1];
  const float* r_ud = (const float*)d_in[2];
  const float* b_ud = (const float*)d_in[3];
  const float* k_du = (const float*)d_in[4];
  const float* r_du = (const float*)d_in[5];
  const float* b_du = (const float*)d_in[6];
  const float* k_lr = (const float*)d_in[7];
  const float* r_lr = (const float*)d_in[8];
  const float* b_lr = (const float*)d_in[9];
  const float* k_rl = (const float*)d_in[10];
  const float* r_rl = (const float*)d_in[11];
  const float* b_rl = (const float*)d_in[12];
  const float* Wd   = (const float*)d_in[13];
  const float* bd   = (const float*)d_in[14];

  ushort* W    = (ushort*)d_ws;
  ushort* Z    = W;                      // Zf: 2*128*65536 uint4 = 268 MB
  ushort* vbuf = Z + 134217728;          // [64][32][32][512]    33554432
  ushort* rF   = vbuf + 33554432;        // [4][64][8][64][8]     1048576
  ushort* kTh  = rF + 1048576;           // [2][1024][512]        1048576
  ushort* WdT  = kTh + 1048576;          // [1024][512]            524288
  uint4* Zf = (uint4*)Z;

  // ---- weight prep ----
  rfrag_kernel<<<128, 256, 0, stream>>>(r_ud, rF);
  rfrag_kernel<<<128, 256, 0, stream>>>(r_du, rF + 262144);
  rfrag_kernel<<<128, 256, 0, stream>>>(r_lr, rF + 524288);
  rfrag_kernel<<<128, 256, 0, stream>>>(r_rl, rF + 786432);
  transpose_bf16<<<2048, 256, 0, stream>>>(k_lr, kTh, 512);
  transpose_bf16<<<2048, 256, 0, stream>>>(k_rl, kTh + 524288, 512);
  transpose_bf16<<<2048, 256, 0, stream>>>(Wd, WdT, 512);

  // ---- vertical input projection (K=12) -> fragment-major Zf ----
  zxv3_kernel<<<dim3(16, 64, 2), 256, 0, stream>>>(x, k_ud, b_ud, k_du, b_du,
                                                   Zf);

  // ---- vertical sweep ----
  lstm_sweep11<<<dim3(128, 2), 1024, 0, stream>>>(Zf, (const uint4*)rF, vbuf,
                                                  1);

  // ---- horizontal input projection: Zf = v @ k + b (per dir) ----
  gemm_bt<0><<<4096, 256, 0, stream>>>(vbuf, kTh, b_lr, (void*)Zf);
  gemm_bt<0><<<4096, 256, 0, stream>>>(vbuf, kTh + 524288, b_rl,
                                       (void*)(Zf + (size_t)128 * 65536));

  // ---- horizontal sweep (writes hfin over vbuf; reads only Zf) ----
  lstm_sweep11<<<dim3(128, 2), 1024, 0, stream>>>(
      Zf, (const uint4*)(rF + 524288), vbuf, 0);

  // ---- dense + relu ----
  gemm_bt<1><<<4096, 256, 0, stream>>>(vbuf, WdT, bd, d_out);
}

// Round 16
// 920.154 us; speedup vs baseline: 1.5614x; 1.4091x over previous
//
#include <hip/hip_runtime.h>
#include <math.h>
#include <stddef.h>
#include <stdint.h>

// ---------------------------------------------------------------------------
// ReNet: patches -> vert bidir LSTM -> horiz bidir LSTM -> dense+relu
// B=64, I=J=32, D=12, HID=256, FC=1024.
// Round 16: sweep reverted to r11's lstm_sweep7 verbatim (254us, the proven
// local optimum; r12-r15 all regressed). Non-sweep work optimized: the two
// horizontal gemms fused into one dual-dir launch (A read once), 4 rfrag
// launches merged, 3 transpose launches merged.
// ---------------------------------------------------------------------------

namespace {

typedef __bf16 bf16x8 __attribute__((ext_vector_type(8)));
typedef float f32x4 __attribute__((ext_vector_type(4)));
typedef __attribute__((address_space(1))) unsigned int as1_uint;
typedef __attribute__((address_space(3))) unsigned int as3_uint;

__device__ __forceinline__ float bf2f(ushort u) {
  return __builtin_bit_cast(float, (unsigned int)u << 16);
}
__device__ __forceinline__ ushort f2bf(float f) {
  unsigned int u = __builtin_bit_cast(unsigned int, f);
  u += 0x7fffu + ((u >> 16) & 1u);
  return (ushort)(u >> 16);
}
__device__ __forceinline__ unsigned int packbf(float a, float b) {
  return (unsigned int)f2bf(a) | ((unsigned int)f2bf(b) << 16);
}
__device__ __forceinline__ float sigm(float x) {
  return __fdividef(1.f, 1.f + __expf(-x));
}
__device__ __forceinline__ float tanh_(float x) {
  return 2.f * sigm(2.f * x) - 1.f;
}
__device__ __forceinline__ f32x4 mfma16(bf16x8 a, bf16x8 b, f32x4 c) {
  return __builtin_amdgcn_mfma_f32_16x16x32_bf16(a, b, c, 0, 0, 0);
}
__device__ __forceinline__ void load_lds16(const void* g, void* l) {
  __builtin_amdgcn_global_load_lds((const as1_uint*)g, (as3_uint*)l, 16, 0, 0);
}

// Zf fragment-major layout, per (dir, rb16) [rb16 = 16-row group, 0..127]:
// 65536 uint4. index = ((seq*2 + q)*2 + p)*512 + tidz ; components = gates.
// uint packs bf16 local rows (2*n2l, 2*n2l+1), n2l = kg*2+p (0..7),
// tidz = w*64 + kg*16 + l16, hcol = w*32 + q*16 + l16.
// dir stride = 128*65536 uint4.

// --------------------------------------------------------------------------
// merged transpose: f32 [512][1024] -> bf16 [1024][512], 3 srcs by blockIdx.y
__global__ __launch_bounds__(256) void transpose_all(
    const float* __restrict__ s0, const float* __restrict__ s1,
    const float* __restrict__ s2, ushort* __restrict__ d0,
    ushort* __restrict__ d1, ushort* __restrict__ d2) {
  const int which = blockIdx.y;
  const float* in = (which == 0) ? s0 : (which == 1) ? s1 : s2;
  ushort* out = (which == 0) ? d0 : (which == 1) ? d1 : d2;
  const int idx = blockIdx.x * 256 + threadIdx.x;  // 524288 ids
  const int n = idx >> 9, k = idx & 511;
  out[idx] = f2bf(in[k * 1024 + n]);
}

// --------------------------------------------------------------------------
// merged rfrag: repack r [256][1024] f32 -> MFMA B-fragment-major bf16,
// 4 srcs by blockIdx.y.
__global__ __launch_bounds__(256) void rfrag_all(
    const float* __restrict__ r0, const float* __restrict__ r1,
    const float* __restrict__ r2, const float* __restrict__ r3,
    ushort* __restrict__ out) {
  const int which = blockIdx.y;
  const float* r = (which == 0) ? r0 : (which == 1) ? r1 : (which == 2) ? r2 : r3;
  ushort* o = out + (size_t)which * 262144;
  const int id = blockIdx.x * 256 + threadIdx.x;  // 32768 ids
  const int lane = id & 63, kc = (id >> 6) & 7, tile = id >> 9;
  const int kbase = (kc << 5) + ((lane >> 4) << 3);
  const int col = (tile << 4) + (lane & 15);
  ushort tmp[8];
#pragma unroll
  for (int j = 0; j < 8; ++j) tmp[j] = f2bf(r[(size_t)(kbase + j) * 1024 + col]);
  *(uint4*)&o[(size_t)id << 3] = *(const uint4*)tmp;
}

// --------------------------------------------------------------------------
// Vertical input projection -> fragment-major Zf. Block (jp, b, dir), 256 thr.
__global__ __launch_bounds__(256) void zxv3_kernel(
    const float* __restrict__ x, const float* __restrict__ k0_,
    const float* __restrict__ b0_, const float* __restrict__ k1_,
    const float* __restrict__ b1_, uint4* __restrict__ Zf) {
  const int tid = threadIdx.x;
  const int jp = blockIdx.x, b = blockIdx.y, dir = blockIdx.z;
  const int j0 = jp << 1;
  const float* kw_ = dir ? k1_ : k0_;
  const float* bw_ = dir ? b1_ : b0_;
  __shared__ float ps[2][32][12];
  for (int e = tid; e < 2 * 32 * 12; e += 256) {
    const int jj = e / 384, rest = e - jj * 384;
    const int i = rest / 12, qq = rest - i * 12;
    const int pr = qq / 6, rem = qq - pr * 6;
    ps[jj][i][qq] =
        x[((size_t)((b * 64 + i * 2 + pr) * 64) + (j0 + jj) * 2 + rem / 3) * 3 + rem % 3];
  }
  __syncthreads();
  float kr[12][4], br[4];
#pragma unroll
  for (int qq = 0; qq < 12; ++qq)
#pragma unroll
    for (int g = 0; g < 4; ++g) kr[qq][g] = kw_[qq * 1024 + (g << 8) + tid];
#pragma unroll
  for (int g = 0; g < 4; ++g) br[g] = bw_[(g << 8) + tid];

  const int wv = tid >> 5, qv = (tid >> 4) & 1, l16v = tid & 15;
  const int rb16 = (b << 1) + (jp >> 3);
  const int n2l = jp & 7;
  const int kgz = n2l >> 1, pz = n2l & 1;
  const int tidz = (wv << 6) + (kgz << 4) + l16v;
  uint4* base = Zf + ((size_t)dir * 128 + rb16) * 65536;

  for (int i = 0; i < 32; ++i) {
    float z0[4], z1[4];
#pragma unroll
    for (int g = 0; g < 4; ++g) { z0[g] = br[g]; z1[g] = br[g]; }
#pragma unroll
    for (int qq = 0; qq < 12; ++qq) {
      const float p0 = ps[0][i][qq], p1 = ps[1][i][qq];
#pragma unroll
      for (int g = 0; g < 4; ++g) {
        z0[g] += p0 * kr[qq][g];
        z1[g] += p1 * kr[qq][g];
      }
    }
    uint4 o;
    o.x = packbf(z0[0], z1[0]);
    o.y = packbf(z0[1], z1[1]);
    o.z = packbf(z0[2], z1[2]);
    o.w = packbf(z0[3], z1[3]);
    base[(size_t)((((i << 1) + qv) << 1) + pz) * 512 + tidz] = o;
  }
}

// --------------------------------------------------------------------------
// Self-contained bidirectional LSTM sweep (r11's lstm_sweep7, verbatim).
// Grid (128 rowblk, 2 dir) = 256 blocks (1/CU), 512 threads (8 waves).
// Block owns rows [rb*16,+16) x all 256 h; wave w owns h-cols [w*32,+32),
// passes q=0,1. acc init = zx (2 coalesced uint4); bfr kc-ring; next-pass zx
// after bfr issues; h in 2x8KB LDS; 1 barrier/step; overlapped out-copy.
__global__ __launch_bounds__(512) void lstm_sweep7(
    const uint4* __restrict__ Zf, const uint4* __restrict__ rF,
    ushort* __restrict__ outbuf, int vert) {
  const int tid = threadIdx.x;
  const int lane = tid & 63, w = tid >> 6;
  const int l16 = lane & 15, kg = lane >> 4;
  const int rb = blockIdx.x, dir = (int)blockIdx.y;
  const int rowbase = rb << 4;

  __shared__ ushort hbuf[2][16 * 256];  // 2 x 8 KB, 16B-chunk XOR swizzle

  const uint4* rFd = rF + (size_t)dir * 32768;  // [64 tiles][8 kc][64 lanes]
  const uint4* zb = Zf + ((size_t)dir * 128 + rb) * 65536;

  float cst[2][4];  // [q][r]
#pragma unroll
  for (int q = 0; q < 2; ++q)
#pragma unroll
    for (int r = 0; r < 4; ++r) cst[q][r] = 0.f;

  uint4 zA[2], zB[2];  // [p], components = gates
  {
    const int seq0 = dir ? 31 : 0;
    zA[0] = zb[(size_t)(seq0 << 2) * 512 + tid];
    zA[1] = zb[(size_t)((seq0 << 2) + 1) * 512 + tid];
  }

  for (int t = 0; t < 32; ++t) {
    const ushort* hprev = hbuf[(t + 1) & 1];
    ushort* hnext = hbuf[t & 1];

    // ---- overlapped out-copy of h(t-1) ----
    if (t) {
      const int seqP = dir ? (32 - t) : (t - 1);
      const int row = tid >> 5, c4 = tid & 31;
      const uint4 v = *(const uint4*)((const char*)hprev + row * 512 +
                                      ((c4 ^ (row & 7)) << 4));
      const int n = rowbase + row, b = n >> 5, sp = n & 31;
      const int X = vert ? seqP : sp, Y = vert ? sp : seqP;
      *(uint4*)&outbuf[(((size_t)(b * 32 + X) * 32 + Y) << 9) + (dir << 8) +
                       (c4 << 3)] = v;
    }

#pragma unroll
    for (int q = 0; q < 2; ++q) {
      uint4(&zc)[2] = (q == 0) ? zA : zB;  // consumed this pass
      uint4(&zn)[2] = (q == 0) ? zB : zA;  // loaded for next pass

      // ---- acc init = zx ----
      f32x4 acc[4];
#pragma unroll
      for (int g = 0; g < 4; ++g) {
        const unsigned int u0 = (g == 0) ? zc[0].x : (g == 1) ? zc[0].y
                                : (g == 2) ? zc[0].z : zc[0].w;
        const unsigned int u1 = (g == 0) ? zc[1].x : (g == 1) ? zc[1].y
                                : (g == 2) ? zc[1].z : zc[1].w;
        acc[g][0] = bf2f((ushort)(u0 & 0xffffu));
        acc[g][1] = bf2f((ushort)(u0 >> 16));
        acc[g][2] = bf2f((ushort)(u1 & 0xffffu));
        acc[g][3] = bf2f((ushort)(u1 >> 16));
      }

      // ---- MFMA: acc += h(t-1) @ R, bfr kc-ring ----
      if (t) {
        uint4 bfr[2][4];
#pragma unroll
        for (int g = 0; g < 4; ++g)
          bfr[0][g] = rFd[(size_t)(((g << 4) + (w << 1) + q) << 3) * 64 + lane];
#pragma unroll
        for (int kc = 0; kc < 8; ++kc) {
          const int cur = kc & 1;
          if (kc < 7) {
#pragma unroll
            for (int g = 0; g < 4; ++g)
              bfr[cur ^ 1][g] =
                  rFd[((size_t)(((g << 4) + (w << 1) + q) << 3) + kc + 1) * 64 +
                      lane];
          }
          const int c4 = (kc << 2) + kg;
          const uint4 a = *(const uint4*)((const char*)hprev + l16 * 512 +
                                          ((c4 ^ (l16 & 7)) << 4));
          const bf16x8 ab = __builtin_bit_cast(bf16x8, a);
#pragma unroll
          for (int g = 0; g < 4; ++g)
            acc[g] = mfma16(ab, __builtin_bit_cast(bf16x8, bfr[cur][g]), acc[g]);
        }
      }

      // ---- issue next-pass zx AFTER all bfr issues ----
      if (t < 31 || q == 0) {
        const int tn = q ? (t + 1) : t;
        const int qn = q ^ 1;
        const int seqn = dir ? (31 - tn) : tn;
        zn[0] = zb[(size_t)(((seqn << 1) + qn) << 1) * 512 + tid];
        zn[1] = zb[(size_t)((((seqn << 1) + qn) << 1) + 1) * 512 + tid];
      }

      // ---- gate epilogue -> h(t) into LDS only ----
      const int col = (w << 5) + (q << 4) + l16;
#pragma unroll
      for (int r = 0; r < 4; ++r) {
        const float zi = acc[0][r];
        const float zf = acc[1][r];
        const float zg = acc[2][r];
        const float zo = acc[3][r];
        const float cn = sigm(zf) * cst[q][r] + sigm(zi) * tanh_(zg);
        cst[q][r] = cn;
        const float hv = sigm(zo) * tanh_(cn);
        const int row = (kg << 2) + r;
        *(ushort*)((char*)hnext + row * 512 +
                   (((col >> 3) ^ (row & 7)) << 4) + ((col & 7) << 1)) =
            f2bf(hv);
      }
    }
    __syncthreads();  // h(t) complete; all h(t-1) reads done
  }

  // ---- final copy of h(31) ----
  {
    const int seqP = dir ? 0 : 31;
    const ushort* hl = hbuf[1];  // t=31 wrote hbuf[1]
    const int row = tid >> 5, c4 = tid & 31;
    const uint4 v = *(const uint4*)((const char*)hl + row * 512 +
                                    ((c4 ^ (row & 7)) << 4));
    const int n = rowbase + row, b = n >> 5, sp = n & 31;
    const int X = vert ? seqP : sp, Y = vert ? sp : seqP;
    *(uint4*)&outbuf[(((size_t)(b * 32 + X) * 32 + Y) << 9) + (dir << 8) +
                     (c4 << 3)] = v;
  }
}

// --------------------------------------------------------------------------
// Dual-dir horizontal projection: Zf[dir] = A @ kTh[dir]^T + bias[dir],
// fragment-major epilogue. 8192 blocks; 16 n-blocks (8 per dir) share one
// A-tile (A read once from HBM). Body = proven gemm_bt<0>.
__global__ __launch_bounds__(256) void gemm_bt_dual(
    const ushort* __restrict__ A, const ushort* __restrict__ BT0,
    const ushort* __restrict__ BT1, const float* __restrict__ bias0,
    const float* __restrict__ bias1, uint4* __restrict__ Zf) {
  const int tid = threadIdx.x;
  const int lane = tid & 63, wid = tid >> 6;
  const int l16 = lane & 15, kg = lane >> 4;
  const int wr = wid >> 1, wc = wid & 1;
  const int bid = blockIdx.x;
  const int xcd = bid & 7, lid = bid >> 3;
  const int m0 = ((xcd << 6) + (lid >> 4)) << 7;
  const int nb = lid & 15;
  const int dirq = nb >> 3;
  const int hc0 = (nb & 7) << 5;
  const ushort* BT = dirq ? BT1 : BT0;
  const float* bias = dirq ? bias1 : bias0;
  uint4* Cz = Zf + (size_t)dirq * 8388608;

  union SM {
    struct { uint4 A[128][8]; uint4 B[128][8]; } k;
    ushort eh[64][136];
  };
  __shared__ SM sm;

  f32x4 acc[4][4];
#pragma unroll
  for (int mt = 0; mt < 4; ++mt)
#pragma unroll
    for (int nt = 0; nt < 4; ++nt) acc[mt][nt] = (f32x4){0.f, 0.f, 0.f, 0.f};

  for (int k0 = 0; k0 < 512; k0 += 64) {
#pragma unroll
    for (int c = 0; c < 4; ++c) {
      const int cid = (wid << 8) + (c << 6) + lane;
      const int row = cid >> 3, ch = cid & 7;
      const int sch = ch ^ (row & 7);
      const int brow = ((row >> 5) << 8) + hc0 + (row & 31);
      load_lds16(A + (size_t)(m0 + row) * 512 + k0 + (sch << 3),
                 (uint4*)sm.k.A + (cid - lane));
      load_lds16(BT + (size_t)brow * 512 + k0 + (sch << 3),
                 (uint4*)sm.k.B + (cid - lane));
    }
    __syncthreads();
#pragma unroll
    for (int kk = 0; kk < 2; ++kk) {
      const int q = (kk << 2) + kg;
      bf16x8 a[4], b[4];
#pragma unroll
      for (int mt = 0; mt < 4; ++mt) {
        const int rr = (wr << 6) + (mt << 4) + l16;
        a[mt] = __builtin_bit_cast(bf16x8, sm.k.A[rr][q ^ (rr & 7)]);
      }
#pragma unroll
      for (int nt = 0; nt < 4; ++nt) {
        const int rr = (wc << 6) + (nt << 4) + l16;
        b[nt] = __builtin_bit_cast(bf16x8, sm.k.B[rr][q ^ (rr & 7)]);
      }
#pragma unroll
      for (int mt = 0; mt < 4; ++mt)
#pragma unroll
        for (int nt = 0; nt < 4; ++nt)
          acc[mt][nt] = mfma16(a[mt], b[nt], acc[mt][nt]);
    }
    __syncthreads();
  }

  float bn[4];
#pragma unroll
  for (int nt = 0; nt < 4; ++nt) {
    const int lcol = (wc << 6) + (nt << 4) + l16;
    bn[nt] = bias[((lcol >> 5) << 8) + hc0 + (lcol & 31)];
  }

#pragma unroll
  for (int h = 0; h < 2; ++h) {
    __syncthreads();
    if (wr == h) {
#pragma unroll
      for (int nt = 0; nt < 4; ++nt) {
        const int col = (wc << 6) + (nt << 4) + l16;
#pragma unroll
        for (int mt = 0; mt < 4; ++mt) {
#pragma unroll
          for (int r = 0; r < 4; ++r) {
            const int rowl = (mt << 4) + (kg << 2) + r;
            sm.eh[rowl][col] = f2bf(acc[mt][nt][r] + bn[nt]);
          }
        }
      }
    }
    __syncthreads();
    // half h covers rows n_a = 2*((m0>>6)+h), n_b = n_a+1, x 32 seq.
    const int n_a = ((m0 >> 6) + h) << 1;
    const int rbz = n_a >> 4;
    const int n2l = (n_a & 15) >> 1;
    const int kgz = n2l >> 1, pz = n2l & 1;
#pragma unroll
    for (int it = 0; it < 4; ++it) {
      const int e = tid + (it << 8);  // 0..1023
      const int seq = e >> 5, hl = e & 31;
      const int qv = hl >> 4, l16v = hl & 15;
      const int wz = (hc0 + hl) >> 5;
      const int tidz = (wz << 6) + (kgz << 4) + l16v;
      uint4 o;
      o.x = (unsigned int)sm.eh[seq][hl] |
            ((unsigned int)sm.eh[32 + seq][hl] << 16);
      o.y = (unsigned int)sm.eh[seq][32 + hl] |
            ((unsigned int)sm.eh[32 + seq][32 + hl] << 16);
      o.z = (unsigned int)sm.eh[seq][64 + hl] |
            ((unsigned int)sm.eh[32 + seq][64 + hl] << 16);
      o.w = (unsigned int)sm.eh[seq][96 + hl] |
            ((unsigned int)sm.eh[32 + seq][96 + hl] << 16);
      Cz[(size_t)rbz * 65536 + (size_t)((((seq << 1) + qv) << 1) + pz) * 512 +
         tidz] = o;
    }
  }
}

// --------------------------------------------------------------------------
// Dense: out = relu(A[M][512] @ WdT[1024][512]^T + bd), f32 stores.
__global__ __launch_bounds__(256) void gemm_dense(
    const ushort* __restrict__ A, const ushort* __restrict__ BT,
    const float* __restrict__ bias, float* __restrict__ out) {
  const int tid = threadIdx.x;
  const int lane = tid & 63, wid = tid >> 6;
  const int l16 = lane & 15, kg = lane >> 4;
  const int wr = wid >> 1, wc = wid & 1;
  const int bid = blockIdx.x;
  const int xcd = bid & 7, lid = bid >> 3;
  const int m0 = ((xcd << 6) + (lid >> 3)) << 7;
  const int n0 = (lid & 7) << 7;

  union SM {
    struct { uint4 A[128][8]; uint4 B[128][8]; } k;
    float ef[64][132];
  };
  __shared__ SM sm;

  f32x4 acc[4][4];
#pragma unroll
  for (int mt = 0; mt < 4; ++mt)
#pragma unroll
    for (int nt = 0; nt < 4; ++nt) acc[mt][nt] = (f32x4){0.f, 0.f, 0.f, 0.f};

  for (int k0 = 0; k0 < 512; k0 += 64) {
#pragma unroll
    for (int c = 0; c < 4; ++c) {
      const int cid = (wid << 8) + (c << 6) + lane;
      const int row = cid >> 3, ch = cid & 7;
      const int sch = ch ^ (row & 7);
      load_lds16(A + (size_t)(m0 + row) * 512 + k0 + (sch << 3),
                 (uint4*)sm.k.A + (cid - lane));
      load_lds16(BT + (size_t)(n0 + row) * 512 + k0 + (sch << 3),
                 (uint4*)sm.k.B + (cid - lane));
    }
    __syncthreads();
#pragma unroll
    for (int kk = 0; kk < 2; ++kk) {
      const int q = (kk << 2) + kg;
      bf16x8 a[4], b[4];
#pragma unroll
      for (int mt = 0; mt < 4; ++mt) {
        const int rr = (wr << 6) + (mt << 4) + l16;
        a[mt] = __builtin_bit_cast(bf16x8, sm.k.A[rr][q ^ (rr & 7)]);
      }
#pragma unroll
      for (int nt = 0; nt < 4; ++nt) {
        const int rr = (wc << 6) + (nt << 4) + l16;
        b[nt] = __builtin_bit_cast(bf16x8, sm.k.B[rr][q ^ (rr & 7)]);
      }
#pragma unroll
      for (int mt = 0; mt < 4; ++mt)
#pragma unroll
        for (int nt = 0; nt < 4; ++nt)
          acc[mt][nt] = mfma16(a[mt], b[nt], acc[mt][nt]);
    }
    __syncthreads();
  }

  float bn[4];
#pragma unroll
  for (int nt = 0; nt < 4; ++nt)
    bn[nt] = bias[n0 + (wc << 6) + (nt << 4) + l16];

#pragma unroll
  for (int h = 0; h < 2; ++h) {
    __syncthreads();
    if (wr == h) {
#pragma unroll
      for (int nt = 0; nt < 4; ++nt) {
        const int col = (wc << 6) + (nt << 4) + l16;
#pragma unroll
        for (int mt = 0; mt < 4; ++mt) {
#pragma unroll
          for (int r = 0; r < 4; ++r) {
            const int rowl = (mt << 4) + (kg << 2) + r;
            sm.ef[rowl][col] = fmaxf(acc[mt][nt][r] + bn[nt], 0.f);
          }
        }
      }
    }
    __syncthreads();
#pragma unroll
    for (int q = 0; q < 8; ++q) {
      const int c = tid + (q << 8);
      const int row = c >> 5, co = (c & 31) << 2;
      const f32x4 v = *(const f32x4*)&sm.ef[row][co];
      __builtin_nontemporal_store(
          v, (f32x4*)(out + (size_t)(m0 + (h << 6) + row) * 1024 + n0 + co));
    }
  }
}

}  // namespace

extern "C" void kernel_launch(void* const* d_in, const int* in_sizes, int n_in,
                              void* d_out, int out_size, void* d_ws, size_t ws_size,
                              hipStream_t stream) {
  (void)in_sizes; (void)n_in; (void)out_size; (void)ws_size;
  const float* x    = (const float*)d_in[0];
  const float* k_ud = (const float*)d_in[1];
  const float* r_ud = (const float*)d_in[2];
  const float* b_ud = (const float*)d_in[3];
  const float* k_du = (const float*)d_in[4];
  const float* r_du = (const float*)d_in[5];
  const float* b_du = (const float*)d_in[6];
  const float* k_lr = (const float*)d_in[7];
  const float* r_lr = (const float*)d_in[8];
  const float* b_lr = (const float*)d_in[9];
  const float* k_rl = (const float*)d_in[10];
  const float* r_rl = (const float*)d_in[11];
  const float* b_rl = (const float*)d_in[12];
  const float* Wd   = (const float*)d_in[13];
  const float* bd   = (const float*)d_in[14];

  ushort* W    = (ushort*)d_ws;
  ushort* Z    = W;                      // Zf: 2*128*65536 uint4 = 268 MB
  ushort* vbuf = Z + 134217728;          // [64][32][32][512]    33554432
  ushort* rF   = vbuf + 33554432;        // [4][64][8][64][8]     1048576
  ushort* kTh  = rF + 1048576;           // [2][1024][512]        1048576
  ushort* WdT  = kTh + 1048576;          // [1024][512]            524288
  uint4* Zf = (uint4*)Z;

  // ---- weight prep (merged launches) ----
  rfrag_all<<<dim3(128, 4), 256, 0, stream>>>(r_ud, r_du, r_lr, r_rl, rF);
  transpose_all<<<dim3(2048, 3), 256, 0, stream>>>(k_lr, k_rl, Wd, kTh,
                                                   kTh + 524288, WdT);

  // ---- vertical input projection (K=12) -> fragment-major Zf ----
  zxv3_kernel<<<dim3(16, 64, 2), 256, 0, stream>>>(x, k_ud, b_ud, k_du, b_du,
                                                   Zf);

  // ---- vertical sweep ----
  lstm_sweep7<<<dim3(128, 2), 512, 0, stream>>>(Zf, (const uint4*)rF, vbuf, 1);

  // ---- horizontal input projection (both dirs, one launch) ----
  gemm_bt_dual<<<8192, 256, 0, stream>>>(vbuf, kTh, kTh + 524288, b_lr, b_rl,
                                         Zf);

  // ---- horizontal sweep (writes hfin over vbuf; reads only Zf) ----
  lstm_sweep7<<<dim3(128, 2), 512, 0, stream>>>(
      Zf, (const uint4*)(rF + 524288), vbuf, 0);

  // ---- dense + relu ----
  gemm_dense<<<4096, 256, 0, stream>>>(vbuf, WdT, bd, (float*)d_out);
}

// Round 17
// 799.265 us; speedup vs baseline: 1.7976x; 1.1512x over previous
//
#include <hip/hip_runtime.h>
#include <math.h>
#include <stddef.h>
#include <stdint.h>

// ---------------------------------------------------------------------------
// ReNet: patches -> vert bidir LSTM -> horiz bidir LSTM -> dense+relu
// B=64, I=J=32, D=12, HID=256, FC=1024.
// Round 17: gemms rebuilt as 8-wave (512-thr) blocks -- 2 waves/SIMD inside
// each block so ds_read->MFMA chains overlap on every SIMD; acc shrinks to
// 32 VGPR/wave (no spill risk); dual epilogue single-pass. Sweeps/prep/zxv
// byte-identical to r16.
// ---------------------------------------------------------------------------

namespace {

typedef __bf16 bf16x8 __attribute__((ext_vector_type(8)));
typedef float f32x4 __attribute__((ext_vector_type(4)));
typedef __attribute__((address_space(1))) unsigned int as1_uint;
typedef __attribute__((address_space(3))) unsigned int as3_uint;

__device__ __forceinline__ float bf2f(ushort u) {
  return __builtin_bit_cast(float, (unsigned int)u << 16);
}
__device__ __forceinline__ ushort f2bf(float f) {
  unsigned int u = __builtin_bit_cast(unsigned int, f);
  u += 0x7fffu + ((u >> 16) & 1u);
  return (ushort)(u >> 16);
}
__device__ __forceinline__ unsigned int packbf(float a, float b) {
  return (unsigned int)f2bf(a) | ((unsigned int)f2bf(b) << 16);
}
__device__ __forceinline__ float sigm(float x) {
  return __fdividef(1.f, 1.f + __expf(-x));
}
__device__ __forceinline__ float tanh_(float x) {
  return 2.f * sigm(2.f * x) - 1.f;
}
__device__ __forceinline__ f32x4 mfma16(bf16x8 a, bf16x8 b, f32x4 c) {
  return __builtin_amdgcn_mfma_f32_16x16x32_bf16(a, b, c, 0, 0, 0);
}
__device__ __forceinline__ void load_lds16(const void* g, void* l) {
  __builtin_amdgcn_global_load_lds((const as1_uint*)g, (as3_uint*)l, 16, 0, 0);
}

// Zf fragment-major layout, per (dir, rb16) [rb16 = 16-row group, 0..127]:
// 65536 uint4. index = ((seq*2 + q)*2 + p)*512 + tidz ; components = gates.
// uint packs bf16 local rows (2*n2l, 2*n2l+1), n2l = kg*2+p (0..7),
// tidz = w*64 + kg*16 + l16, hcol = w*32 + q*16 + l16.
// dir stride = 128*65536 uint4.

// --------------------------------------------------------------------------
// merged transpose: f32 [512][1024] -> bf16 [1024][512], 3 srcs by blockIdx.y
__global__ __launch_bounds__(256) void transpose_all(
    const float* __restrict__ s0, const float* __restrict__ s1,
    const float* __restrict__ s2, ushort* __restrict__ d0,
    ushort* __restrict__ d1, ushort* __restrict__ d2) {
  const int which = blockIdx.y;
  const float* in = (which == 0) ? s0 : (which == 1) ? s1 : s2;
  ushort* out = (which == 0) ? d0 : (which == 1) ? d1 : d2;
  const int idx = blockIdx.x * 256 + threadIdx.x;  // 524288 ids
  const int n = idx >> 9, k = idx & 511;
  out[idx] = f2bf(in[k * 1024 + n]);
}

// --------------------------------------------------------------------------
// merged rfrag: repack r [256][1024] f32 -> MFMA B-fragment-major bf16,
// 4 srcs by blockIdx.y.
__global__ __launch_bounds__(256) void rfrag_all(
    const float* __restrict__ r0, const float* __restrict__ r1,
    const float* __restrict__ r2, const float* __restrict__ r3,
    ushort* __restrict__ out) {
  const int which = blockIdx.y;
  const float* r = (which == 0) ? r0 : (which == 1) ? r1 : (which == 2) ? r2 : r3;
  ushort* o = out + (size_t)which * 262144;
  const int id = blockIdx.x * 256 + threadIdx.x;  // 32768 ids
  const int lane = id & 63, kc = (id >> 6) & 7, tile = id >> 9;
  const int kbase = (kc << 5) + ((lane >> 4) << 3);
  const int col = (tile << 4) + (lane & 15);
  ushort tmp[8];
#pragma unroll
  for (int j = 0; j < 8; ++j) tmp[j] = f2bf(r[(size_t)(kbase + j) * 1024 + col]);
  *(uint4*)&o[(size_t)id << 3] = *(const uint4*)tmp;
}

// --------------------------------------------------------------------------
// Vertical input projection -> fragment-major Zf. Block (jp, b, dir), 256 thr.
__global__ __launch_bounds__(256) void zxv3_kernel(
    const float* __restrict__ x, const float* __restrict__ k0_,
    const float* __restrict__ b0_, const float* __restrict__ k1_,
    const float* __restrict__ b1_, uint4* __restrict__ Zf) {
  const int tid = threadIdx.x;
  const int jp = blockIdx.x, b = blockIdx.y, dir = blockIdx.z;
  const int j0 = jp << 1;
  const float* kw_ = dir ? k1_ : k0_;
  const float* bw_ = dir ? b1_ : b0_;
  __shared__ float ps[2][32][12];
  for (int e = tid; e < 2 * 32 * 12; e += 256) {
    const int jj = e / 384, rest = e - jj * 384;
    const int i = rest / 12, qq = rest - i * 12;
    const int pr = qq / 6, rem = qq - pr * 6;
    ps[jj][i][qq] =
        x[((size_t)((b * 64 + i * 2 + pr) * 64) + (j0 + jj) * 2 + rem / 3) * 3 + rem % 3];
  }
  __syncthreads();
  float kr[12][4], br[4];
#pragma unroll
  for (int qq = 0; qq < 12; ++qq)
#pragma unroll
    for (int g = 0; g < 4; ++g) kr[qq][g] = kw_[qq * 1024 + (g << 8) + tid];
#pragma unroll
  for (int g = 0; g < 4; ++g) br[g] = bw_[(g << 8) + tid];

  const int wv = tid >> 5, qv = (tid >> 4) & 1, l16v = tid & 15;
  const int rb16 = (b << 1) + (jp >> 3);
  const int n2l = jp & 7;
  const int kgz = n2l >> 1, pz = n2l & 1;
  const int tidz = (wv << 6) + (kgz << 4) + l16v;
  uint4* base = Zf + ((size_t)dir * 128 + rb16) * 65536;

  for (int i = 0; i < 32; ++i) {
    float z0[4], z1[4];
#pragma unroll
    for (int g = 0; g < 4; ++g) { z0[g] = br[g]; z1[g] = br[g]; }
#pragma unroll
    for (int qq = 0; qq < 12; ++qq) {
      const float p0 = ps[0][i][qq], p1 = ps[1][i][qq];
#pragma unroll
      for (int g = 0; g < 4; ++g) {
        z0[g] += p0 * kr[qq][g];
        z1[g] += p1 * kr[qq][g];
      }
    }
    uint4 o;
    o.x = packbf(z0[0], z1[0]);
    o.y = packbf(z0[1], z1[1]);
    o.z = packbf(z0[2], z1[2]);
    o.w = packbf(z0[3], z1[3]);
    base[(size_t)((((i << 1) + qv) << 1) + pz) * 512 + tidz] = o;
  }
}

// --------------------------------------------------------------------------
// Self-contained bidirectional LSTM sweep (r11's lstm_sweep7, verbatim).
__global__ __launch_bounds__(512) void lstm_sweep7(
    const uint4* __restrict__ Zf, const uint4* __restrict__ rF,
    ushort* __restrict__ outbuf, int vert) {
  const int tid = threadIdx.x;
  const int lane = tid & 63, w = tid >> 6;
  const int l16 = lane & 15, kg = lane >> 4;
  const int rb = blockIdx.x, dir = (int)blockIdx.y;
  const int rowbase = rb << 4;

  __shared__ ushort hbuf[2][16 * 256];  // 2 x 8 KB, 16B-chunk XOR swizzle

  const uint4* rFd = rF + (size_t)dir * 32768;  // [64 tiles][8 kc][64 lanes]
  const uint4* zb = Zf + ((size_t)dir * 128 + rb) * 65536;

  float cst[2][4];  // [q][r]
#pragma unroll
  for (int q = 0; q < 2; ++q)
#pragma unroll
    for (int r = 0; r < 4; ++r) cst[q][r] = 0.f;

  uint4 zA[2], zB[2];  // [p], components = gates
  {
    const int seq0 = dir ? 31 : 0;
    zA[0] = zb[(size_t)(seq0 << 2) * 512 + tid];
    zA[1] = zb[(size_t)((seq0 << 2) + 1) * 512 + tid];
  }

  for (int t = 0; t < 32; ++t) {
    const ushort* hprev = hbuf[(t + 1) & 1];
    ushort* hnext = hbuf[t & 1];

    // ---- overlapped out-copy of h(t-1) ----
    if (t) {
      const int seqP = dir ? (32 - t) : (t - 1);
      const int row = tid >> 5, c4 = tid & 31;
      const uint4 v = *(const uint4*)((const char*)hprev + row * 512 +
                                      ((c4 ^ (row & 7)) << 4));
      const int n = rowbase + row, b = n >> 5, sp = n & 31;
      const int X = vert ? seqP : sp, Y = vert ? sp : seqP;
      *(uint4*)&outbuf[(((size_t)(b * 32 + X) * 32 + Y) << 9) + (dir << 8) +
                       (c4 << 3)] = v;
    }

#pragma unroll
    for (int q = 0; q < 2; ++q) {
      uint4(&zc)[2] = (q == 0) ? zA : zB;  // consumed this pass
      uint4(&zn)[2] = (q == 0) ? zB : zA;  // loaded for next pass

      // ---- acc init = zx ----
      f32x4 acc[4];
#pragma unroll
      for (int g = 0; g < 4; ++g) {
        const unsigned int u0 = (g == 0) ? zc[0].x : (g == 1) ? zc[0].y
                                : (g == 2) ? zc[0].z : zc[0].w;
        const unsigned int u1 = (g == 0) ? zc[1].x : (g == 1) ? zc[1].y
                                : (g == 2) ? zc[1].z : zc[1].w;
        acc[g][0] = bf2f((ushort)(u0 & 0xffffu));
        acc[g][1] = bf2f((ushort)(u0 >> 16));
        acc[g][2] = bf2f((ushort)(u1 & 0xffffu));
        acc[g][3] = bf2f((ushort)(u1 >> 16));
      }

      // ---- MFMA: acc += h(t-1) @ R, bfr kc-ring ----
      if (t) {
        uint4 bfr[2][4];
#pragma unroll
        for (int g = 0; g < 4; ++g)
          bfr[0][g] = rFd[(size_t)(((g << 4) + (w << 1) + q) << 3) * 64 + lane];
#pragma unroll
        for (int kc = 0; kc < 8; ++kc) {
          const int cur = kc & 1;
          if (kc < 7) {
#pragma unroll
            for (int g = 0; g < 4; ++g)
              bfr[cur ^ 1][g] =
                  rFd[((size_t)(((g << 4) + (w << 1) + q) << 3) + kc + 1) * 64 +
                      lane];
          }
          const int c4 = (kc << 2) + kg;
          const uint4 a = *(const uint4*)((const char*)hprev + l16 * 512 +
                                          ((c4 ^ (l16 & 7)) << 4));
          const bf16x8 ab = __builtin_bit_cast(bf16x8, a);
#pragma unroll
          for (int g = 0; g < 4; ++g)
            acc[g] = mfma16(ab, __builtin_bit_cast(bf16x8, bfr[cur][g]), acc[g]);
        }
      }

      // ---- issue next-pass zx AFTER all bfr issues ----
      if (t < 31 || q == 0) {
        const int tn = q ? (t + 1) : t;
        const int qn = q ^ 1;
        const int seqn = dir ? (31 - tn) : tn;
        zn[0] = zb[(size_t)(((seqn << 1) + qn) << 1) * 512 + tid];
        zn[1] = zb[(size_t)((((seqn << 1) + qn) << 1) + 1) * 512 + tid];
      }

      // ---- gate epilogue -> h(t) into LDS only ----
      const int col = (w << 5) + (q << 4) + l16;
#pragma unroll
      for (int r = 0; r < 4; ++r) {
        const float zi = acc[0][r];
        const float zf = acc[1][r];
        const float zg = acc[2][r];
        const float zo = acc[3][r];
        const float cn = sigm(zf) * cst[q][r] + sigm(zi) * tanh_(zg);
        cst[q][r] = cn;
        const float hv = sigm(zo) * tanh_(cn);
        const int row = (kg << 2) + r;
        *(ushort*)((char*)hnext + row * 512 +
                   (((col >> 3) ^ (row & 7)) << 4) + ((col & 7) << 1)) =
            f2bf(hv);
      }
    }
    __syncthreads();  // h(t) complete; all h(t-1) reads done
  }

  // ---- final copy of h(31) ----
  {
    const int seqP = dir ? 0 : 31;
    const ushort* hl = hbuf[1];  // t=31 wrote hbuf[1]
    const int row = tid >> 5, c4 = tid & 31;
    const uint4 v = *(const uint4*)((const char*)hl + row * 512 +
                                    ((c4 ^ (row & 7)) << 4));
    const int n = rowbase + row, b = n >> 5, sp = n & 31;
    const int X = vert ? seqP : sp, Y = vert ? sp : seqP;
    *(uint4*)&outbuf[(((size_t)(b * 32 + X) * 32 + Y) << 9) + (dir << 8) +
                     (c4 << 3)] = v;
  }
}

// --------------------------------------------------------------------------
// Dual-dir horizontal projection, 8-wave blocks (512 thr): Zf[dir] =
// A @ kTh[dir]^T + bias[dir], fragment-major epilogue staged in one pass.
// Wave grid 4m x 2n over the 128x128 tile; per-wave 32x64 -> acc[2][4].
__global__ __launch_bounds__(512) void gemm_bt_dual(
    const ushort* __restrict__ A, const ushort* __restrict__ BT0,
    const ushort* __restrict__ BT1, const float* __restrict__ bias0,
    const float* __restrict__ bias1, uint4* __restrict__ Zf) {
  const int tid = threadIdx.x;
  const int lane = tid & 63, wid = tid >> 6;
  const int l16 = lane & 15, kg = lane >> 4;
  const int wr = wid >> 1, wc = wid & 1;  // 4m x 2n
  const int bid = blockIdx.x;
  const int xcd = bid & 7, lid = bid >> 3;
  const int m0 = ((xcd << 6) + (lid >> 4)) << 7;
  const int nb = lid & 15;
  const int dirq = nb >> 3;
  const int hc0 = (nb & 7) << 5;
  const ushort* BT = dirq ? BT1 : BT0;
  const float* bias = dirq ? bias1 : bias0;
  uint4* Cz = Zf + (size_t)dirq * 8388608;

  union SM {
    struct { uint4 A[128][8]; uint4 B[128][8]; } k;
    ushort eh[128][136];
  };
  __shared__ SM sm;

  f32x4 acc[2][4];
#pragma unroll
  for (int mt = 0; mt < 2; ++mt)
#pragma unroll
    for (int nt = 0; nt < 4; ++nt) acc[mt][nt] = (f32x4){0.f, 0.f, 0.f, 0.f};

  for (int k0 = 0; k0 < 512; k0 += 64) {
#pragma unroll
    for (int c = 0; c < 2; ++c) {
      const int cid = (wid << 7) + (c << 6) + lane;  // 0..1023
      const int row = cid >> 3, ch = cid & 7;
      const int sch = ch ^ (row & 7);
      const int brow = ((row >> 5) << 8) + hc0 + (row & 31);
      load_lds16(A + (size_t)(m0 + row) * 512 + k0 + (sch << 3),
                 (uint4*)sm.k.A + (cid - lane));
      load_lds16(BT + (size_t)brow * 512 + k0 + (sch << 3),
                 (uint4*)sm.k.B + (cid - lane));
    }
    __syncthreads();
#pragma unroll
    for (int kk = 0; kk < 2; ++kk) {
      const int q = (kk << 2) + kg;
      bf16x8 a[2], b[4];
#pragma unroll
      for (int mt = 0; mt < 2; ++mt) {
        const int rr = (wr << 5) + (mt << 4) + l16;
        a[mt] = __builtin_bit_cast(bf16x8, sm.k.A[rr][q ^ (rr & 7)]);
      }
#pragma unroll
      for (int nt = 0; nt < 4; ++nt) {
        const int rr = (wc << 6) + (nt << 4) + l16;
        b[nt] = __builtin_bit_cast(bf16x8, sm.k.B[rr][q ^ (rr & 7)]);
      }
#pragma unroll
      for (int mt = 0; mt < 2; ++mt)
#pragma unroll
        for (int nt = 0; nt < 4; ++nt)
          acc[mt][nt] = mfma16(a[mt], b[nt], acc[mt][nt]);
    }
    __syncthreads();
  }

  float bn[4];
#pragma unroll
  for (int nt = 0; nt < 4; ++nt) {
    const int lcol = (wc << 6) + (nt << 4) + l16;
    bn[nt] = bias[((lcol >> 5) << 8) + hc0 + (lcol & 31)];
  }

  // stage ALL 128 rows at once (eh aliases k stage; all LDS reads done)
#pragma unroll
  for (int mt = 0; mt < 2; ++mt) {
#pragma unroll
    for (int nt = 0; nt < 4; ++nt) {
      const int col = (wc << 6) + (nt << 4) + l16;
#pragma unroll
      for (int r = 0; r < 4; ++r) {
        const int rowl = (wr << 5) + (mt << 4) + (kg << 2) + r;
        sm.eh[rowl][col] = f2bf(acc[mt][nt][r] + bn[nt]);
      }
    }
  }
  __syncthreads();

#pragma unroll
  for (int h = 0; h < 2; ++h) {
    // n-pair n2 = (m0>>6)+h covers local rows [h*64, h*64+64)
    const int n_a = ((m0 >> 6) + h) << 1;
    const int rbz = n_a >> 4;
    const int n2l = (n_a & 15) >> 1;
    const int kgz = n2l >> 1, pz = n2l & 1;
#pragma unroll
    for (int it = 0; it < 2; ++it) {
      const int e = tid + (it << 9);  // 0..1023
      const int seq = e >> 5, hl = e & 31;
      const int qv = hl >> 4, l16v = hl & 15;
      const int wz = (hc0 + hl) >> 5;
      const int tidz = (wz << 6) + (kgz << 4) + l16v;
      uint4 o;
      o.x = (unsigned int)sm.eh[(h << 6) + seq][hl] |
            ((unsigned int)sm.eh[(h << 6) + 32 + seq][hl] << 16);
      o.y = (unsigned int)sm.eh[(h << 6) + seq][32 + hl] |
            ((unsigned int)sm.eh[(h << 6) + 32 + seq][32 + hl] << 16);
      o.z = (unsigned int)sm.eh[(h << 6) + seq][64 + hl] |
            ((unsigned int)sm.eh[(h << 6) + 32 + seq][64 + hl] << 16);
      o.w = (unsigned int)sm.eh[(h << 6) + seq][96 + hl] |
            ((unsigned int)sm.eh[(h << 6) + 32 + seq][96 + hl] << 16);
      Cz[(size_t)rbz * 65536 + (size_t)((((seq << 1) + qv) << 1) + pz) * 512 +
         tidz] = o;
    }
  }
}

// --------------------------------------------------------------------------
// Dense, 8-wave blocks (512 thr): out = relu(A @ WdT^T + bd), f32 stores.
__global__ __launch_bounds__(512) void gemm_dense(
    const ushort* __restrict__ A, const ushort* __restrict__ BT,
    const float* __restrict__ bias, float* __restrict__ out) {
  const int tid = threadIdx.x;
  const int lane = tid & 63, wid = tid >> 6;
  const int l16 = lane & 15, kg = lane >> 4;
  const int wr = wid >> 1, wc = wid & 1;  // 4m x 2n
  const int bid = blockIdx.x;
  const int xcd = bid & 7, lid = bid >> 3;
  const int m0 = ((xcd << 6) + (lid >> 3)) << 7;
  const int n0 = (lid & 7) << 7;

  union SM {
    struct { uint4 A[128][8]; uint4 B[128][8]; } k;
    float ef[64][132];
  };
  __shared__ SM sm;

  f32x4 acc[2][4];
#pragma unroll
  for (int mt = 0; mt < 2; ++mt)
#pragma unroll
    for (int nt = 0; nt < 4; ++nt) acc[mt][nt] = (f32x4){0.f, 0.f, 0.f, 0.f};

  for (int k0 = 0; k0 < 512; k0 += 64) {
#pragma unroll
    for (int c = 0; c < 2; ++c) {
      const int cid = (wid << 7) + (c << 6) + lane;  // 0..1023
      const int row = cid >> 3, ch = cid & 7;
      const int sch = ch ^ (row & 7);
      load_lds16(A + (size_t)(m0 + row) * 512 + k0 + (sch << 3),
                 (uint4*)sm.k.A + (cid - lane));
      load_lds16(BT + (size_t)(n0 + row) * 512 + k0 + (sch << 3),
                 (uint4*)sm.k.B + (cid - lane));
    }
    __syncthreads();
#pragma unroll
    for (int kk = 0; kk < 2; ++kk) {
      const int q = (kk << 2) + kg;
      bf16x8 a[2], b[4];
#pragma unroll
      for (int mt = 0; mt < 2; ++mt) {
        const int rr = (wr << 5) + (mt << 4) + l16;
        a[mt] = __builtin_bit_cast(bf16x8, sm.k.A[rr][q ^ (rr & 7)]);
      }
#pragma unroll
      for (int nt = 0; nt < 4; ++nt) {
        const int rr = (wc << 6) + (nt << 4) + l16;
        b[nt] = __builtin_bit_cast(bf16x8, sm.k.B[rr][q ^ (rr & 7)]);
      }
#pragma unroll
      for (int mt = 0; mt < 2; ++mt)
#pragma unroll
        for (int nt = 0; nt < 4; ++nt)
          acc[mt][nt] = mfma16(a[mt], b[nt], acc[mt][nt]);
    }
    __syncthreads();
  }

  float bn[4];
#pragma unroll
  for (int nt = 0; nt < 4; ++nt)
    bn[nt] = bias[n0 + (wc << 6) + (nt << 4) + l16];

#pragma unroll
  for (int h = 0; h < 2; ++h) {
    __syncthreads();
    if ((wr >> 1) == h) {  // waves wr in {2h, 2h+1} own rows [h*64, +64)
#pragma unroll
      for (int mt = 0; mt < 2; ++mt) {
#pragma unroll
        for (int nt = 0; nt < 4; ++nt) {
          const int col = (wc << 6) + (nt << 4) + l16;
#pragma unroll
          for (int r = 0; r < 4; ++r) {
            const int rowl = ((wr & 1) << 5) + (mt << 4) + (kg << 2) + r;
            sm.ef[rowl][col] = fmaxf(acc[mt][nt][r] + bn[nt], 0.f);
          }
        }
      }
    }
    __syncthreads();
#pragma unroll
    for (int it = 0; it < 4; ++it) {
      const int c = tid + (it << 9);  // 0..2047
      const int row = c >> 5, co = (c & 31) << 2;
      const f32x4 v = *(const f32x4*)&sm.ef[row][co];
      __builtin_nontemporal_store(
          v, (f32x4*)(out + (size_t)(m0 + (h << 6) + row) * 1024 + n0 + co));
    }
  }
}

}  // namespace

extern "C" void kernel_launch(void* const* d_in, const int* in_sizes, int n_in,
                              void* d_out, int out_size, void* d_ws, size_t ws_size,
                              hipStream_t stream) {
  (void)in_sizes; (void)n_in; (void)out_size; (void)ws_size;
  const float* x    = (const float*)d_in[0];
  const float* k_ud = (const float*)d_in[1];
  const float* r_ud = (const float*)d_in[2];
  const float* b_ud = (const float*)d_in[3];
  const float* k_du = (const float*)d_in[4];
  const float* r_du = (const float*)d_in[5];
  const float* b_du = (const float*)d_in[6];
  const float* k_lr = (const float*)d_in[7];
  const float* r_lr = (const float*)d_in[8];
  const float* b_lr = (const float*)d_in[9];
  const float* k_rl = (const float*)d_in[10];
  const float* r_rl = (const float*)d_in[11];
  const float* b_rl = (const float*)d_in[12];
  const float* Wd   = (const float*)d_in[13];
  const float* bd   = (const float*)d_in[14];

  ushort* W    = (ushort*)d_ws;
  ushort* Z    = W;                      // Zf: 2*128*65536 uint4 = 268 MB
  ushort* vbuf = Z + 134217728;          // [64][32][32][512]    33554432
  ushort* rF   = vbuf + 33554432;        // [4][64][8][64][8]     1048576
  ushort* kTh  = rF + 1048576;           // [2][1024][512]        1048576
  ushort* WdT  = kTh + 1048576;          // [1024][512]            524288
  uint4* Zf = (uint4*)Z;

  // ---- weight prep (merged launches) ----
  rfrag_all<<<dim3(128, 4), 256, 0, stream>>>(r_ud, r_du, r_lr, r_rl, rF);
  transpose_all<<<dim3(2048, 3), 256, 0, stream>>>(k_lr, k_rl, Wd, kTh,
                                                   kTh + 524288, WdT);

  // ---- vertical input projection (K=12) -> fragment-major Zf ----
  zxv3_kernel<<<dim3(16, 64, 2), 256, 0, stream>>>(x, k_ud, b_ud, k_du, b_du,
                                                   Zf);

  // ---- vertical sweep ----
  lstm_sweep7<<<dim3(128, 2), 512, 0, stream>>>(Zf, (const uint4*)rF, vbuf, 1);

  // ---- horizontal input projection (both dirs, one launch, 8-wave) ----
  gemm_bt_dual<<<8192, 512, 0, stream>>>(vbuf, kTh, kTh + 524288, b_lr, b_rl,
                                         Zf);

  // ---- horizontal sweep (writes hfin over vbuf; reads only Zf) ----
  lstm_sweep7<<<dim3(128, 2), 512, 0, stream>>>(
      Zf, (const uint4*)(rF + 524288), vbuf, 0);

  // ---- dense + relu (8-wave) ----
  gemm_dense<<<4096, 512, 0, stream>>>(vbuf, WdT, bd, (float*)d_out);
}